// Round 1
// baseline (384.174 us; speedup 1.0000x reference)
//
#include <hip/hip_runtime.h>
#include <math.h>

#define NUM_LOD 8
#define NLDS 4            // LODs 0..3 (16^2+23^2+35^2+52^2 cells = 37712 B) live in LDS
#define BLOCK 512
#define ITERS 4           // points per block = (BLOCK/2) * ITERS = 1024
#define LDS_F 9428        // floats: (256+529+1225+2704)*2

struct GridParams {
    const float* cb[NUM_LOD];
    int res[NUM_LOD];
    int ldsOff[NLDS];     // float offsets into cbLds
    int ldsCnt[NLDS];     // float counts
};

// Lane-pair LOD split: even lane = LODs 0-3 (LDS), odd lane = LODs 4-7 (L2).
// Each lane holds exactly 2 output float4 quads -> direct stores, no transpose
// buffer, no extra barriers. __launch_bounds__(512,8) forces VGPR<=64 so LDS
// (37.7KB -> 4 blocks/CU) gives 32 waves/CU.
__global__ __launch_bounds__(BLOCK, 8) void densegrid_kernel(
    const float2* __restrict__ pts, GridParams p, float4* __restrict__ out4, long long n)
{
    __shared__ float cbLds[LDS_F];
    const int t = threadIdx.x;

    // Phase A: stage LODs 0-3 (coalesced float2 stream from L2)
    for (int L = 0; L < NLDS; ++L) {
        const float2* src = (const float2*)p.cb[L];
        float2* dst = (float2*)&cbLds[p.ldsOff[L]];
        const int cnt2 = p.ldsCnt[L] >> 1;
        for (int j = t; j < cnt2; j += BLOCK) dst[j] = src[j];
    }
    __syncthreads();

    const int half  = t & 1;     // 0: LODs 0-3 (LDS), 1: LODs 4-7 (global/L2)
    const int pslot = t >> 1;    // point slot within chunk (0..BLOCK/2-1)

    // Per-thread LOD constants, selected ONCE (j compile-time, half runtime)
    float sc[4];
    int   rs[4];
    const float2* gptr[4];       // global codebook ptrs (odd lanes)
    int   loff[4];               // float2 offsets into cbLds (even lanes)
#pragma unroll
    for (int j = 0; j < 4; ++j) {
        const int L = half ? (4 + j) : j;
        rs[j]  = p.res[L];
        sc[j]  = (float)(rs[j] - 1);
        gptr[j] = (const float2*)p.cb[4 + j];
        loff[j] = p.ldsOff[j] >> 1;
    }

    const long long base = (long long)blockIdx.x * (BLOCK / 2) * ITERS;

#pragma unroll 1
    for (int it = 0; it < ITERS; ++it) {
        const long long P = base + (long long)it * (BLOCK / 2) + pslot;
        if (P < n) {
            const float2 pt = pts[P];   // lane pairs dup-load same addr -> HW broadcast
            float vx[4], vy[4];
            if (half) {
#pragma unroll
                for (int j = 0; j < 4; ++j) {
                    const int ix = (int)(pt.x * sc[j]);   // x in [0,1): trunc == floor
                    const int iy = (int)(pt.y * sc[j]);
                    const float2 f = gptr[j][ix + iy * rs[j]];  // L2 gather
                    vx[j] = f.x; vy[j] = f.y;
                }
            } else {
                const float2* ldsF2 = (const float2*)cbLds;
#pragma unroll
                for (int j = 0; j < 4; ++j) {
                    const int ix = (int)(pt.x * sc[j]);
                    const int iy = (int)(pt.y * sc[j]);
                    const float2 f = ldsF2[loff[j] + ix + iy * rs[j]];  // LDS gather
                    vx[j] = f.x; vy[j] = f.y;
                }
            }
            // Row of point P = [x(L0..L7), y(L0..L7)] = quads q0..q3.
            // even lane: q0 (x0-3), q2 (y0-3); odd lane: q1 (x4-7), q3 (y4-7)
            const long long m4 = (P << 2) + half;
            out4[m4]     = make_float4(vx[0], vx[1], vx[2], vx[3]);
            out4[m4 + 2] = make_float4(vy[0], vy[1], vy[2], vy[3]);
        }
    }
}

extern "C" void kernel_launch(void* const* d_in, const int* in_sizes, int n_in,
                              void* d_out, int out_size, void* d_ws, size_t ws_size,
                              hipStream_t stream)
{
    const float2* pts = (const float2*)d_in[0];
    const long long n = in_sizes[0] / 2;

    GridParams p;
    int off = 0;
    for (int L = 0; L < NUM_LOD; ++L) {
        p.cb[L] = (const float*)d_in[L + 1];
        const int cells = in_sizes[L + 1] / 2;           // res*res
        p.res[L] = (int)(sqrt((double)cells) + 0.5);     // derive res exactly from size
        if (L < NLDS) {
            p.ldsOff[L] = off;
            p.ldsCnt[L] = in_sizes[L + 1];
            off += in_sizes[L + 1];
        }
    }

    const long long ppb  = (long long)(BLOCK / 2) * ITERS;
    const long long grid = (n + ppb - 1) / ppb;
    densegrid_kernel<<<(int)grid, BLOCK, 0, stream>>>(pts, p, (float4*)d_out, n);
}

// Round 2
// 377.665 us; speedup vs baseline: 1.0172x; 1.0172x over previous
//
#include <hip/hip_runtime.h>
#include <math.h>

#define NUM_LOD 8
#define NLDS 4            // LODs 0..3 (16^2+23^2+35^2+52^2 cells = 37712 B) in LDS
#define BLOCK 512
#define ITERS 4           // points per block = (BLOCK/2) * ITERS = 1024
#define LDS_F 9428        // floats: (256+529+1225+2704)*2

typedef float f4 __attribute__((ext_vector_type(4)));

struct GridParams {
    const float* cb[NUM_LOD];
    int res[NUM_LOD];
    int ldsOff[NLDS];     // float offsets into cbLds
    int ldsCnt[NLDS];     // float counts
};

// Lane-pair LOD split: even lane = LODs 0-3 (LDS), odd lane = LODs 4-7 (L2).
// Each lane natively holds 2 output quads -> direct stores, no transpose, no
// barriers. v2 fixes vs last round:
//  - NO per-thread param arrays: p.res/p.cb read directly from kernarg SGPRs
//    inside the branch (compile-time index) -> ~50 VGPR, (512,8) is now safe.
//  - unroll 2 on the point loop -> 8 outstanding gathers/thread (MLP back).
//  - nontemporal stores: 256MB write-once stream must not evict the ~1MB of
//    L2-resident codebooks the gathers depend on.
__global__ __launch_bounds__(BLOCK, 8) void densegrid_kernel(
    const float2* __restrict__ pts, GridParams p, f4* __restrict__ out4, long long n)
{
    __shared__ float cbLds[LDS_F];
    const int t = threadIdx.x;

    // Phase A: stage LODs 0-3 (coalesced float2 stream from L2)
    for (int L = 0; L < NLDS; ++L) {
        const float2* src = (const float2*)p.cb[L];
        float2* dst = (float2*)&cbLds[p.ldsOff[L]];
        const int cnt2 = p.ldsCnt[L] >> 1;
        for (int j = t; j < cnt2; j += BLOCK) dst[j] = src[j];
    }
    __syncthreads();

    const int half  = t & 1;     // 0: LODs 0-3 (LDS), 1: LODs 4-7 (global/L2)
    const int pslot = t >> 1;    // point slot within chunk (0..BLOCK/2-1)
    const long long base = (long long)blockIdx.x * (BLOCK / 2) * ITERS;

#pragma unroll 2
    for (int it = 0; it < ITERS; ++it) {
        const long long P = base + (long long)it * (BLOCK / 2) + pslot;
        if (P < n) {
            const float2 pt = pts[P];   // lane pairs dup-load same addr (HW merges)
            float vx[4], vy[4];
            if (half) {
#pragma unroll
                for (int j = 0; j < 4; ++j) {
                    const int   res = p.res[4 + j];          // SGPR (kernarg)
                    const float sc  = (float)(res - 1);
                    const int ix = (int)(pt.x * sc);         // x in [0,1): trunc==floor
                    const int iy = (int)(pt.y * sc);
                    const float2 f = ((const float2*)p.cb[4 + j])[ix + iy * res]; // L2
                    vx[j] = f.x; vy[j] = f.y;
                }
            } else {
                const float2* ldsF2 = (const float2*)cbLds;
#pragma unroll
                for (int j = 0; j < 4; ++j) {
                    const int   res = p.res[j];              // SGPR (kernarg)
                    const float sc  = (float)(res - 1);
                    const int ix = (int)(pt.x * sc);
                    const int iy = (int)(pt.y * sc);
                    const float2 f = ldsF2[(p.ldsOff[j] >> 1) + ix + iy * res];   // LDS
                    vx[j] = f.x; vy[j] = f.y;
                }
            }
            // Row of point P = [x(L0..L7), y(L0..L7)] = quads q0..q3.
            // even lane: q0,q2; odd lane: q1,q3 -> pairwise 32B-dense stores.
            const long long m4 = (P << 2) + half;
            f4 a = {vx[0], vx[1], vx[2], vx[3]};
            f4 b = {vy[0], vy[1], vy[2], vy[3]};
            __builtin_nontemporal_store(a, &out4[m4]);
            __builtin_nontemporal_store(b, &out4[m4 + 2]);
        }
    }
}

extern "C" void kernel_launch(void* const* d_in, const int* in_sizes, int n_in,
                              void* d_out, int out_size, void* d_ws, size_t ws_size,
                              hipStream_t stream)
{
    const float2* pts = (const float2*)d_in[0];
    const long long n = in_sizes[0] / 2;

    GridParams p;
    int off = 0;
    for (int L = 0; L < NUM_LOD; ++L) {
        p.cb[L] = (const float*)d_in[L + 1];
        const int cells = in_sizes[L + 1] / 2;           // res*res
        p.res[L] = (int)(sqrt((double)cells) + 0.5);     // derive res exactly from size
        if (L < NLDS) {
            p.ldsOff[L] = off;
            p.ldsCnt[L] = in_sizes[L + 1];
            off += in_sizes[L + 1];
        }
    }

    const long long ppb  = (long long)(BLOCK / 2) * ITERS;
    const long long grid = (n + ppb - 1) / ppb;
    densegrid_kernel<<<(int)grid, BLOCK, 0, stream>>>(pts, p, (f4*)d_out, n);
}

// Round 3
// 343.507 us; speedup vs baseline: 1.1184x; 1.0994x over previous
//
#include <hip/hip_runtime.h>
#include <math.h>

#define NUM_LOD 8
#define NLDS 3            // LODs 0..2 (16^2, 23^2, 35^2 cells = 16080 B) live in LDS
#define BLOCK 512
#define PPT 2             // points per thread -> 10 outstanding L2 gathers/thread
#define TPAD 17           // transpose stride in floats (odd -> conflict-free)

struct GridParams {
    const float* cb[NUM_LOD];
    int res[NUM_LOD];
    int ldsOff[NLDS];
    int ldsCnt[NLDS];
};

// Round-0 verified structure (kernel ~24us, bounded by L2/L3 store absorption):
//  - Phase B issues all PPT*8 gathers independently -> full MLP by construction.
//  - Phase C LDS transpose -> fully-dense float4 stores (critical: the output
//    fits Infinity Cache; dense cached stores ride ~13 TB/s L2/L3 absorption.
//    Do NOT use nontemporal stores here - they pin the store path to HBM's
//    6.3 TB/s and cost ~2.5x kernel time, measured round 2).
//  - 50% -dense or strided store patterns double L2 store transactions on the
//    bottleneck pipe (measured round 1: kernel 24 -> 66 us).
__global__ __launch_bounds__(BLOCK) void densegrid_kernel(
    const float2* __restrict__ pts, GridParams p, float4* __restrict__ out4, long long n)
{
    __shared__ float cbLds[4096];          // 16080 B of small codebooks
    __shared__ float tbuf[BLOCK * TPAD];   // 34.8 KB transpose buffer (reused PPT times)

    const int t = threadIdx.x;

    // Phase A: stage small codebooks (coalesced float2 stream, L2 source)
    for (int L = 0; L < NLDS; ++L) {
        const float2* src = (const float2*)p.cb[L];
        float2* dst = (float2*)&cbLds[p.ldsOff[L]];
        const int cnt2 = p.ldsCnt[L] >> 1;
        for (int j = t; j < cnt2; j += BLOCK) dst[j] = src[j];
    }
    __syncthreads();

    // Phase B: PPT points per thread; all global gathers independent -> high MLP
    const long long base = (long long)blockIdx.x * (BLOCK * PPT);
    long long pi[PPT];
    float2 pt[PPT];
#pragma unroll
    for (int s = 0; s < PPT; ++s) {
        pi[s] = base + (long long)s * BLOCK + t;
        if (pi[s] < n) pt[s] = pts[pi[s]];     // coalesced
    }

    float o[PPT][16];
#pragma unroll
    for (int s = 0; s < PPT; ++s) {
        if (pi[s] >= n) continue;
#pragma unroll
        for (int L = 0; L < NUM_LOD; ++L) {
            const int   res = p.res[L];
            const float sc  = (float)(res - 1);
            const int ix = (int)floorf(pt[s].x * sc);
            const int iy = (int)floorf(pt[s].y * sc);
            const int idx = ix + iy * res;
            float2 f;
            if (L < NLDS) f = ((const float2*)&cbLds[p.ldsOff[L]])[idx];  // LDS gather
            else          f = ((const float2*)p.cb[L])[idx];              // L2 gather
            o[s][L]     = f.x;      // out[n, 0*8 + L]
            o[s][8 + L] = f.y;      // out[n, 1*8 + L]
        }
    }

    // Phase C: per point-chunk, LDS transpose then block-coalesced float4 stores
    const long long lim4 = n * 4;
#pragma unroll
    for (int s = 0; s < PPT; ++s) {
        if (s > 0) __syncthreads();            // protect tbuf reuse
        if (pi[s] < n) {
#pragma unroll
            for (int j = 0; j < 16; ++j) tbuf[t * TPAD + j] = o[s][j];
        }
        __syncthreads();
        const long long b4 = (base + (long long)s * BLOCK) * 4;
#pragma unroll
        for (int k = 0; k < 4; ++k) {
            const int m = k * BLOCK + t;       // float4 index within chunk
            const long long g = b4 + m;
            if (g < lim4) {
                const int pnt = m >> 2, q = m & 3;
                const float* src = &tbuf[pnt * TPAD + q * 4];
                out4[g] = make_float4(src[0], src[1], src[2], src[3]);
            }
        }
    }
}

extern "C" void kernel_launch(void* const* d_in, const int* in_sizes, int n_in,
                              void* d_out, int out_size, void* d_ws, size_t ws_size,
                              hipStream_t stream)
{
    const float2* pts = (const float2*)d_in[0];
    const long long n = in_sizes[0] / 2;

    GridParams p;
    int off = 0;
    for (int L = 0; L < NUM_LOD; ++L) {
        p.cb[L] = (const float*)d_in[L + 1];
        const int cells = in_sizes[L + 1] / 2;           // res*res
        p.res[L] = (int)(sqrt((double)cells) + 0.5);     // derive res exactly from size
        if (L < NLDS) {
            p.ldsOff[L] = off;
            p.ldsCnt[L] = in_sizes[L + 1];
            off += in_sizes[L + 1];
        }
    }

    const long long grid = (n + (long long)(BLOCK * PPT) - 1) / (BLOCK * PPT);
    densegrid_kernel<<<(int)grid, BLOCK, 0, stream>>>(pts, p, (float4*)d_out, n);
}